// Round 9
// baseline (484.441 us; speedup 1.0000x reference)
//
#include <hip/hip_runtime.h>
#include <hip/hip_bf16.h>

#define M_TOK 16384   // B*S
#define DDIM  1024
#define NEXP  8
#define KP    (NEXP * DDIM)   // 8192 fused K

typedef __bf16 bf16x8 __attribute__((ext_vector_type(8)));
typedef __bf16 bf16x4 __attribute__((ext_vector_type(4)));
typedef float  floatx4 __attribute__((ext_vector_type(4)));

__device__ __forceinline__ void gload_lds16(const void* g, void* l) {
    __builtin_amdgcn_global_load_lds(
        (__attribute__((address_space(1))) void*)(void*)g,
        (__attribute__((address_space(3))) void*)l,
        16, 0, 0);
}

// ---------------------------------------------------------------------------
// Kernel 1 (merged prep): blocks [0,2048) convert W_edges fp32 -> Bp bf16
// [f][e*1024+k]; blocks [2048,2560) route: 32 rows/block (8/wave), Wr staged
// once per block. R6 finding: prep internals are NOT on the critical path.
// ---------------------------------------------------------------------------
#define CONV_BLOCKS  2048
#define ROUTE_BLOCKS 512   // 32 rows per block

__global__ __launch_bounds__(256) void prep_kernel(
    const float* __restrict__ h, const float* __restrict__ Wr,
    const float* __restrict__ br, const float* __restrict__ We,
    __bf16* __restrict__ hbf, float* __restrict__ rw, __bf16* __restrict__ Bp)
{
    __shared__ float Wrs[NEXP * DDIM];
    const int tid = threadIdx.x;

    if (blockIdx.x < CONV_BLOCKS) {
        size_t idx = ((size_t)blockIdx.x * 256 + tid) * 16;
        int e = (int)(idx >> 20);
        int f = (int)(idx >> 10) & 1023;
        int k = (int)idx & 1023;
        const float4* s4 = (const float4*)(We + idx);
        float a[16];
        #pragma unroll
        for (int i = 0; i < 4; ++i) {
            float4 v = s4[i];
            a[i*4+0] = v.x; a[i*4+1] = v.y; a[i*4+2] = v.z; a[i*4+3] = v.w;
        }
        bf16x8 o0, o1;
        #pragma unroll
        for (int i = 0; i < 8; ++i) { o0[i] = (__bf16)a[i]; o1[i] = (__bf16)a[8 + i]; }
        __bf16* d = Bp + (size_t)f * KP + (size_t)e * DDIM + k;
        *(bf16x8*)d       = o0;
        *(bf16x8*)(d + 8) = o1;
        return;
    }

    // ---- route: stage Wr once, then 8 rows per wave
    {
        const float4* s4 = (const float4*)Wr;
        float4* d4 = (float4*)Wrs;
        #pragma unroll
        for (int j = 0; j < 8; ++j) d4[j * 256 + tid] = s4[j * 256 + tid];
    }
    __syncthreads();

    const int wave = tid >> 6, lane = tid & 63;
    const int mbase = (blockIdx.x - CONV_BLOCKS) * 32 + wave * 8;
    const float4* Wrs4 = (const float4*)Wrs;

    #pragma unroll 2
    for (int i = 0; i < 8; ++i) {
        const int m = mbase + i;
        const float4* hrow4 = (const float4*)(h + (size_t)m * DDIM);
        float4 a[4];
        #pragma unroll
        for (int j = 0; j < 4; ++j) a[j] = hrow4[j * 64 + lane];

        #pragma unroll
        for (int j = 0; j < 4; ++j) {
            bf16x4 o;
            o[0] = (__bf16)a[j].x; o[1] = (__bf16)a[j].y;
            o[2] = (__bf16)a[j].z; o[3] = (__bf16)a[j].w;
            *(bf16x4*)(hbf + (size_t)m * DDIM + j * 256 + lane * 4) = o;
        }

        float p[NEXP];
        #pragma unroll
        for (int e = 0; e < NEXP; ++e) {
            float s = 0.f;
            #pragma unroll
            for (int j = 0; j < 4; ++j) {
                float4 wv = Wrs4[e * 256 + j * 64 + lane];
                s += a[j].x*wv.x + a[j].y*wv.y + a[j].z*wv.z + a[j].w*wv.w;
            }
            p[e] = s;
        }
        #pragma unroll
        for (int e = 0; e < NEXP; ++e) {
            #pragma unroll
            for (int off = 32; off > 0; off >>= 1)
                p[e] += __shfl_xor(p[e], off, 64);
        }
        if (lane == 0) {
            float l[NEXP], mx = -1e30f;
            #pragma unroll
            for (int e = 0; e < NEXP; ++e) { l[e] = p[e] + br[e]; mx = fmaxf(mx, l[e]); }
            float s = 0.f;
            #pragma unroll
            for (int e = 0; e < NEXP; ++e) { l[e] = expf(l[e] - mx); s += l[e]; }
            float inv = 1.f / s;
            float4 r0 = {l[0]*inv, l[1]*inv, l[2]*inv, l[3]*inv};
            float4 r1 = {l[4]*inv, l[5]*inv, l[6]*inv, l[7]*inv};
            *(float4*)(rw + (size_t)m * NEXP)     = r0;
            *(float4*)(rw + (size_t)m * NEXP + 4) = r1;
        }
    }
}

// ---------------------------------------------------------------------------
// Kernel 2: fused MoE GEMM — R9 restructure: 128x128 tile, 4 waves (2x2),
// 256 threads, LDS 68.5 KiB -> TWO blocks per CU (was 1). Rationale: R2-R8
// proved the intra-block schedule is barrier-lockstep-serial (observed
// cyc/tile = LDS floor + MFMA floor exactly); two independent barrier
// domains per CU let block A's LDS phase overlap block B's MFMA phase
// (m114 mechanism). Tile body = proven R8 schedule, re-parameterized.
//
// Grid 1024 = 128 m-tiles x 8 f-panels. XCD map: f0=(L&7)*128 -> each XCD
// owns one f-panel whose B-slice (128 x 8192 bf16 = 2 MiB) is L2-resident.
//
// Per K-32 tile (ring-4 LDS slots of 8 KiB, distance-2 staging, 4 loads/tile):
//   [vmcnt(4); bar]  ph1 {ds bv[4]+av[0..1], stage A(t+2); bar;
//                         setprio1; 8 MFMA mf0-1; setprio0}
//                    ph2 {ds av[2..3],       stage B(t+2); bar;
//                         setprio1; 8 MFMA mf2-3; setprio0}
// Hazards: RAW — tile t's 4 loads are the 4 oldest at t's gate -> vmcnt(4)
// + barrier publishes. WAR — stage targets slot u+2, last read at t-2,
// >= 3 barriers earlier. Identical FIFO argument to R3/R8.
//
// Expert rescale invariant: entering expert e, facc = (sum_{i<e} w_i*C_i)/w_e;
// boundary multiplies by w_{e-1}/w_e; epilogue multiplies by w_7.
// rws padded stride 9. Swizzle algebra unchanged (depends on row bits 1-2).
// ---------------------------------------------------------------------------
__global__ __launch_bounds__(256, 2) void gemm_fused_kernel(
    const __bf16* __restrict__ hbf, const __bf16* __restrict__ Bp,
    const float* __restrict__ rw, const float* __restrict__ bias,
    float* __restrict__ outp)
{
    __shared__ __bf16 As[4][128 * 32];   // 4 x 8 KiB
    __shared__ __bf16 Bs[4][128 * 32];   // 4 x 8 KiB
    __shared__ float  rws[128 * 9];      // 4.5 KiB, padded stride 9

    const int tid  = threadIdx.x;
    const int wave = tid >> 6, lane = tid & 63;
    const int quad = lane >> 4, l16 = lane & 15;
    const int wm = wave >> 1, wn = wave & 1;          // 2 x 2 wave grid

    // XCD map: xcd = L&7 -> f-panel; m-tile = L>>3.
    const int L = blockIdx.x;
    const int f0 = (L & 7) * 128;
    const int m0 = (L >> 3) * 128;

    // stage routing weights for this block's 128 rows into padded LDS
    if (tid < 128) {
        const float4* s = (const float4*)(rw + ((size_t)m0 + tid) * NEXP);
        float4 x0 = s[0], x1 = s[1];
        float* d = &rws[tid * 9];
        d[0] = x0.x; d[1] = x0.y; d[2] = x0.z; d[3] = x0.w;
        d[4] = x1.x; d[5] = x1.y; d[6] = x1.z; d[7] = x1.w;
    }

    // LDS read offsets: row = 64B (4 groups of 16B); group swizzle g^=(row>>1)&3.
    // mf/nf steps of 16 rows (=1024B) leave the swizzle bits unchanged.
    const int arow = wm * 64 + l16;
    const int brow = wn * 64 + l16;
    const int aoff0 = (arow * 4 + (quad ^ ((arow >> 1) & 3))) * 16;
    const int boff0 = (brow * 4 + (quad ^ ((brow >> 1) & 3))) * 16;

    // staging: chunk c (c=0,1) dst byte = c*4096 + tid*16; row = c*64 + (tid>>2);
    // pre-swizzled global source group (row+64 preserves (row>>1)&3)
    const int srow = tid >> 2;
    const int scol = ((tid & 3) ^ ((srow >> 1) & 3)) * 8;
    const size_t aBase = (size_t)(m0 + srow) * DDIM + scol;
    const size_t bBase = (size_t)(f0 + srow) * KP + scol;

    floatx4 facc[4][4];
    const floatx4 z4 = {0.f, 0.f, 0.f, 0.f};
    #pragma unroll
    for (int i = 0; i < 4; ++i)
        #pragma unroll
        for (int j = 0; j < 4; ++j) facc[i][j] = z4;

    __syncthreads();   // rws visible

    // prologue: stage tiles 0 (oldest 4 loads) and 1
    #pragma unroll
    for (int t = 0; t < 2; ++t) {
        const __bf16* a0 = hbf + aBase + (t << 5);
        const __bf16* b0 = Bp  + bBase + (t << 5);
        char* ad = (char*)&As[t][0] + tid * 16;
        char* bd = (char*)&Bs[t][0] + tid * 16;
        gload_lds16(a0,           ad);
        gload_lds16(a0 + 65536,   ad + 4096);   // +64 rows (64*DDIM)
        gload_lds16(b0,           bd);
        gload_lds16(b0 + 524288,  bd + 4096);   // +64 rows (64*KP)
    }

    #pragma unroll 1
    for (int tb = 0; tb < 64; ++tb) {
        if (tb && (tb & 7) == 0) {
            const int e = tb >> 3;   // entering expert e
            #pragma unroll
            for (int mf = 0; mf < 4; ++mf) {
                #pragma unroll
                for (int r = 0; r < 4; ++r) {
                    int row = wm * 64 + mf * 16 + quad * 4 + r;
                    float wp = fmaxf(rws[row * 9 + e - 1], 1e-20f);
                    float wc = fmaxf(rws[row * 9 + e],     1e-20f);
                    float ratio = wp / wc;
                    #pragma unroll
                    for (int nf = 0; nf < 4; ++nf) facc[mf][nf][r] *= ratio;
                }
            }
        }
        #pragma unroll
        for (int u = 0; u < 4; ++u) {
            const int t  = (tb << 2) + u;
            const int tt = (t + 2) & 255;               // staged tile (wrap: harmless)
            const __bf16* asrc = hbf + aBase + (size_t)((tt & 31) << 5);
            const __bf16* bsrc = Bp  + bBase + ((size_t)tt << 5);
            char* ad = (char*)&As[(u + 2) & 3][0] + tid * 16;
            char* bd = (char*)&Bs[(u + 2) & 3][0] + tid * 16;
            const char* Ab = (const char*)&As[u][0];
            const char* Bb = (const char*)&Bs[u][0];

            asm volatile("s_waitcnt vmcnt(4)" ::: "memory");
            asm volatile("s_barrier" ::: "memory");

            // ---- phase 1: fragments bv[4]+av[0..1]; stage next A-tile
            bf16x8 av[4], bv[4];
            #pragma unroll
            for (int nf = 0; nf < 4; ++nf)
                bv[nf] = *(const bf16x8*)(Bb + boff0 + nf * 1024);
            av[0] = *(const bf16x8*)(Ab + aoff0);
            av[1] = *(const bf16x8*)(Ab + aoff0 + 1024);
            gload_lds16(asrc,         ad);
            gload_lds16(asrc + 65536, ad + 4096);

            asm volatile("s_barrier" ::: "memory");
            __builtin_amdgcn_s_setprio(1);
            #pragma unroll
            for (int mf = 0; mf < 2; ++mf)
                #pragma unroll
                for (int nf = 0; nf < 4; ++nf)
                    facc[mf][nf] = __builtin_amdgcn_mfma_f32_16x16x32_bf16(
                        av[mf], bv[nf], facc[mf][nf], 0, 0, 0);
            __builtin_amdgcn_s_setprio(0);

            // ---- phase 2: fragments av[2..3]; stage next B-tile
            av[2] = *(const bf16x8*)(Ab + aoff0 + 2048);
            av[3] = *(const bf16x8*)(Ab + aoff0 + 3072);
            gload_lds16(bsrc,          bd);
            gload_lds16(bsrc + 524288, bd + 4096);

            asm volatile("s_barrier" ::: "memory");
            __builtin_amdgcn_s_setprio(1);
            #pragma unroll
            for (int mf = 2; mf < 4; ++mf)
                #pragma unroll
                for (int nf = 0; nf < 4; ++nf)
                    facc[mf][nf] = __builtin_amdgcn_mfma_f32_16x16x32_bf16(
                        av[mf], bv[nf], facc[mf][nf], 0, 0, 0);
            __builtin_amdgcn_s_setprio(0);
        }
    }

    // drain pending global_load_lds before epilogue / LDS reuse
    asm volatile("s_waitcnt vmcnt(0)" ::: "memory");

    // epilogue: out = GELU(facc * w_7 + bias)
    float bval[4];
    #pragma unroll
    for (int nf = 0; nf < 4; ++nf) bval[nf] = bias[f0 + wn * 64 + nf * 16 + l16];
    #pragma unroll
    for (int mf = 0; mf < 4; ++mf) {
        #pragma unroll
        for (int r = 0; r < 4; ++r) {
            int lrow = wm * 64 + mf * 16 + quad * 4 + r;
            int gm = m0 + lrow;
            float w7 = fmaxf(rws[lrow * 9 + 7], 1e-20f);
            #pragma unroll
            for (int nf = 0; nf < 4; ++nf) {
                float x = facc[mf][nf][r] * w7 + bval[nf];
                float gel = 0.5f * x * (1.0f + erff(x * 0.70710678118f));
                outp[(size_t)gm * DDIM + (f0 + wn * 64 + nf * 16 + l16)] = gel;
            }
        }
    }
}

// ---------------------------------------------------------------------------
extern "C" void kernel_launch(void* const* d_in, const int* in_sizes, int n_in,
                              void* d_out, int out_size, void* d_ws, size_t ws_size,
                              hipStream_t stream) {
    const float* h    = (const float*)d_in[0];   // [4,4096,1024]
    const float* Wr   = (const float*)d_in[1];   // [8,1024]
    const float* br   = (const float*)d_in[2];   // [8]
    const float* We   = (const float*)d_in[3];   // [8,1024,1024]
    const float* bias = (const float*)d_in[4];   // [1024]
    float* outp = (float*)d_out;
    char* ws = (char*)d_ws;

    __bf16* hbf = (__bf16*)ws;                                   // 32 MiB
    __bf16* Bp  = (__bf16*)(ws + (size_t)M_TOK * DDIM * 2);      // 16 MiB
    float*  rwp = (float*)(ws + (size_t)M_TOK * DDIM * 2
                              + (size_t)NEXP * DDIM * DDIM * 2); // 512 KiB

    hipLaunchKernelGGL(prep_kernel, dim3(CONV_BLOCKS + ROUTE_BLOCKS), dim3(256),
                       0, stream, h, Wr, br, We, hbf, rwp, Bp);
    hipLaunchKernelGGL(gemm_fused_kernel, dim3(1024), dim3(256),
                       0, stream, hbf, Bp, rwp, bias, outp);
}

// Round 10
// 412.198 us; speedup vs baseline: 1.1753x; 1.1753x over previous
//
#include <hip/hip_runtime.h>
#include <hip/hip_bf16.h>

#define M_TOK 16384   // B*S
#define DDIM  1024
#define NEXP  8
#define KP    (NEXP * DDIM)   // 8192 fused K

typedef __bf16 bf16x8 __attribute__((ext_vector_type(8)));
typedef __bf16 bf16x4 __attribute__((ext_vector_type(4)));
typedef float  floatx4 __attribute__((ext_vector_type(4)));

__device__ __forceinline__ void gload_lds16(const void* g, void* l) {
    __builtin_amdgcn_global_load_lds(
        (__attribute__((address_space(1))) void*)(void*)g,
        (__attribute__((address_space(3))) void*)l,
        16, 0, 0);
}

// ---------------------------------------------------------------------------
// Kernel 1 (merged prep): blocks [0,2048) convert W_edges fp32 -> Bp bf16
// [f][e*1024+k]; blocks [2048,2560) route: 32 rows/block (8/wave), Wr staged
// once per block. R6 finding: prep internals are NOT on the critical path.
// ---------------------------------------------------------------------------
#define CONV_BLOCKS  2048
#define ROUTE_BLOCKS 512   // 32 rows per block

__global__ __launch_bounds__(256) void prep_kernel(
    const float* __restrict__ h, const float* __restrict__ Wr,
    const float* __restrict__ br, const float* __restrict__ We,
    __bf16* __restrict__ hbf, float* __restrict__ rw, __bf16* __restrict__ Bp)
{
    __shared__ float Wrs[NEXP * DDIM];
    const int tid = threadIdx.x;

    if (blockIdx.x < CONV_BLOCKS) {
        size_t idx = ((size_t)blockIdx.x * 256 + tid) * 16;
        int e = (int)(idx >> 20);
        int f = (int)(idx >> 10) & 1023;
        int k = (int)idx & 1023;
        const float4* s4 = (const float4*)(We + idx);
        float a[16];
        #pragma unroll
        for (int i = 0; i < 4; ++i) {
            float4 v = s4[i];
            a[i*4+0] = v.x; a[i*4+1] = v.y; a[i*4+2] = v.z; a[i*4+3] = v.w;
        }
        bf16x8 o0, o1;
        #pragma unroll
        for (int i = 0; i < 8; ++i) { o0[i] = (__bf16)a[i]; o1[i] = (__bf16)a[8 + i]; }
        __bf16* d = Bp + (size_t)f * KP + (size_t)e * DDIM + k;
        *(bf16x8*)d       = o0;
        *(bf16x8*)(d + 8) = o1;
        return;
    }

    // ---- route: stage Wr once, then 8 rows per wave
    {
        const float4* s4 = (const float4*)Wr;
        float4* d4 = (float4*)Wrs;
        #pragma unroll
        for (int j = 0; j < 8; ++j) d4[j * 256 + tid] = s4[j * 256 + tid];
    }
    __syncthreads();

    const int wave = tid >> 6, lane = tid & 63;
    const int mbase = (blockIdx.x - CONV_BLOCKS) * 32 + wave * 8;
    const float4* Wrs4 = (const float4*)Wrs;

    #pragma unroll 2
    for (int i = 0; i < 8; ++i) {
        const int m = mbase + i;
        const float4* hrow4 = (const float4*)(h + (size_t)m * DDIM);
        float4 a[4];
        #pragma unroll
        for (int j = 0; j < 4; ++j) a[j] = hrow4[j * 64 + lane];

        #pragma unroll
        for (int j = 0; j < 4; ++j) {
            bf16x4 o;
            o[0] = (__bf16)a[j].x; o[1] = (__bf16)a[j].y;
            o[2] = (__bf16)a[j].z; o[3] = (__bf16)a[j].w;
            *(bf16x4*)(hbf + (size_t)m * DDIM + j * 256 + lane * 4) = o;
        }

        float p[NEXP];
        #pragma unroll
        for (int e = 0; e < NEXP; ++e) {
            float s = 0.f;
            #pragma unroll
            for (int j = 0; j < 4; ++j) {
                float4 wv = Wrs4[e * 256 + j * 64 + lane];
                s += a[j].x*wv.x + a[j].y*wv.y + a[j].z*wv.z + a[j].w*wv.w;
            }
            p[e] = s;
        }
        #pragma unroll
        for (int e = 0; e < NEXP; ++e) {
            #pragma unroll
            for (int off = 32; off > 0; off >>= 1)
                p[e] += __shfl_xor(p[e], off, 64);
        }
        if (lane == 0) {
            float l[NEXP], mx = -1e30f;
            #pragma unroll
            for (int e = 0; e < NEXP; ++e) { l[e] = p[e] + br[e]; mx = fmaxf(mx, l[e]); }
            float s = 0.f;
            #pragma unroll
            for (int e = 0; e < NEXP; ++e) { l[e] = expf(l[e] - mx); s += l[e]; }
            float inv = 1.f / s;
            float4 r0 = {l[0]*inv, l[1]*inv, l[2]*inv, l[3]*inv};
            float4 r1 = {l[4]*inv, l[5]*inv, l[6]*inv, l[7]*inv};
            *(float4*)(rw + (size_t)m * NEXP)     = r0;
            *(float4*)(rw + (size_t)m * NEXP + 4) = r1;
        }
    }
}

// ---------------------------------------------------------------------------
// Kernel 2: fused MoE GEMM — R10: R8's proven 256x256/8-wave/ring-4 structure
// + TILE-LEVEL REGISTER PIPELINE. R2-R9 showed cyc/tile = LDS floor + MFMA
// floor (serial): every MFMA burst depended on same-window ds_reads. Now at
// tile t the waves read fragments of t while MFMAing fragments of t-1 (in
// registers) -> LDS pipe and matrix pipe busy simultaneously every phase.
//   gate(t): vmcnt(4); barrier
//   ph1: read bv(t)->fb[u&1], av0(t); stage A(t+2); barrier;
//        MFMA hi(t-1) from fa1[prev],fb[prev]   (skipped at t=0)
//        [expert-boundary rescale here: hi(t-1)=old expert, lo(t)=new]
//   ph2: read av1(t)->fa1[u&1]; stage B(t+2); barrier;
//        MFMA lo(t) from av0,fb[u&1]
// Epilogue adds hi(255). hi/lo touch disjoint facc halves; all ordering is
// register dataflow (MFMA may drift across barriers harmlessly - rule 18
// applies only to memory hazards, and slot lifetimes are unchanged from R8).
// Frag double-buffer indexed by u&1 (u fully unrolled -> static, rule 20).
// VGPR budget: ~20 b128 frags (80) + addr (~45) + 128 AGPR acc ~= 252/wave;
// 8 waves x 252 = 2016 < 2048 pool. If VGPR_Count >~135 or occupancy ~11%,
// this failed the budget - revert.
//
// Hazards (identical to R8; reads still occur in tile t's own window):
//  RAW: tile t's 4 loads are the 4 oldest at gate(t) -> vmcnt(4)+bar.
//  WAR: stage at t targets slot u+2, last READ at t-2, >= 3 barriers before.
//
// Expert rescale invariant: entering expert e, facc = (sum_{i<e} w_i*C_i)/w_e;
// boundary multiplies by w_{e-1}/w_e; epilogue multiplies by w_7.
// ---------------------------------------------------------------------------
__global__ __launch_bounds__(512, 2) void gemm_fused_kernel(
    const __bf16* __restrict__ hbf, const __bf16* __restrict__ Bp,
    const float* __restrict__ rw, const float* __restrict__ bias,
    float* __restrict__ outp)
{
    __shared__ __bf16 As[4][256 * 32];   // 4 x 16 KiB
    __shared__ __bf16 Bs[4][256 * 32];   // 4 x 16 KiB
    __shared__ float  rws[256 * 9];      // 9 KiB, padded stride 9

    const int tid  = threadIdx.x;
    const int wave = tid >> 6, lane = tid & 63;
    const int quad = lane >> 4, l16 = lane & 15;
    const int wm = wave >> 2, wn = wave & 3;          // 2 x 4 wave grid

    // Bijective XCD map: two XCDs per f-panel; B-slice L2-resident.
    const int L = blockIdx.x;
    const int xcd = L & 7, slotid = L >> 3;
    const int f0 = (xcd >> 1) * 256;
    const int m0 = (((xcd & 1) << 5) + slotid) * 256;

    // stage routing weights for this block's 256 rows into padded LDS
    if (tid < 256) {
        const float4* s = (const float4*)(rw + ((size_t)m0 + tid) * NEXP);
        float4 x0 = s[0], x1 = s[1];
        float* d = &rws[tid * 9];
        d[0] = x0.x; d[1] = x0.y; d[2] = x0.z; d[3] = x0.w;
        d[4] = x1.x; d[5] = x1.y; d[6] = x1.z; d[7] = x1.w;
    }

    // LDS read offsets: row = 64B (4 groups of 16B); group swizzle g^=(row>>1)&3.
    const int arow = wm * 128 + l16;
    const int brow = wn * 64  + l16;
    const int aoff0 = (arow * 4 + (quad ^ ((arow >> 1) & 3))) * 16;
    const int boff0 = (brow * 4 + (quad ^ ((brow >> 1) & 3))) * 16;

    // staging: chunk c dst byte = c*8192 + tid*16; row = c*128 + (tid>>2);
    // pre-swizzled global source group (row+128 preserves (row>>1)&3)
    const int srow = tid >> 2;
    const int scol = ((tid & 3) ^ ((srow >> 1) & 3)) * 8;
    const size_t aBase = (size_t)(m0 + srow) * DDIM + scol;
    const size_t bBase = (size_t)(f0 + srow) * KP + scol;

    floatx4 facc[8][4];
    const floatx4 z4 = {0.f, 0.f, 0.f, 0.f};
    #pragma unroll
    for (int i = 0; i < 8; ++i)
        #pragma unroll
        for (int j = 0; j < 4; ++j) facc[i][j] = z4;

    // fragment double-buffers carried across tiles (set index = u&1, static)
    bf16x8 fb[2][4];    // bv(t) sets
    bf16x8 fa1[2][4];   // av1(t) sets

    __syncthreads();   // rws visible

    // prologue: stage tiles 0 (oldest 4 loads) and 1
    {
        const __bf16* a0 = hbf + aBase;
        const __bf16* b0 = Bp  + bBase;
        gload_lds16(a0,                 (char*)&As[0][0] + tid * 16);
        gload_lds16(b0,                 (char*)&Bs[0][0] + tid * 16);
        gload_lds16(a0 + 131072,        (char*)&As[0][0] + tid * 16 + 8192);
        gload_lds16(b0 + 1048576,       (char*)&Bs[0][0] + tid * 16 + 8192);
        gload_lds16(a0 + 32,            (char*)&As[1][0] + tid * 16);
        gload_lds16(b0 + 32,            (char*)&Bs[1][0] + tid * 16);
        gload_lds16(a0 + 131072 + 32,   (char*)&As[1][0] + tid * 16 + 8192);
        gload_lds16(b0 + 1048576 + 32,  (char*)&Bs[1][0] + tid * 16 + 8192);
    }

    #pragma unroll 1
    for (int tb = 0; tb < 64; ++tb) {
        #pragma unroll
        for (int u = 0; u < 4; ++u) {
            const int t  = (tb << 2) + u;
            const int cs = u & 1, ps = cs ^ 1;          // cur/prev frag sets
            const int tt = (t + 2) & 255;               // staged tile
            const __bf16* asrc = hbf + aBase + (size_t)((tt & 31) << 5);
            const __bf16* bsrc = Bp  + bBase + ((size_t)tt << 5);
            char* ad = (char*)&As[(u + 2) & 3][0] + tid * 16;
            char* bd = (char*)&Bs[(u + 2) & 3][0] + tid * 16;
            const char* Ab = (const char*)&As[u][0];
            const char* Bb = (const char*)&Bs[u][0];

            asm volatile("s_waitcnt vmcnt(4)" ::: "memory");
            asm volatile("s_barrier" ::: "memory");

            // ---- ph1: read bv(t), av0(t); stage A(t+2)
            bf16x8 av0[4];
            #pragma unroll
            for (int nf = 0; nf < 4; ++nf)
                fb[cs][nf] = *(const bf16x8*)(Bb + boff0 + nf * 1024);
            #pragma unroll
            for (int mf = 0; mf < 4; ++mf)
                av0[mf] = *(const bf16x8*)(Ab + aoff0 + mf * 1024);
            gload_lds16(asrc,          ad);
            gload_lds16(asrc + 131072, ad + 8192);

            asm volatile("s_barrier" ::: "memory");

            // ---- MFMA hi(t-1) from prev frag sets (registers)
            if (u > 0 || tb > 0) {
                __builtin_amdgcn_s_setprio(1);
                #pragma unroll
                for (int mf = 0; mf < 4; ++mf)
                    #pragma unroll
                    for (int nf = 0; nf < 4; ++nf)
                        facc[4 + mf][nf] = __builtin_amdgcn_mfma_f32_16x16x32_bf16(
                            fa1[ps][mf], fb[ps][nf], facc[4 + mf][nf], 0, 0, 0);
                __builtin_amdgcn_s_setprio(0);
            }

            // expert boundary: hi(t-1) above was old expert's last; rescale
            // before lo(t) (new expert's first). Dataflow-ordered via facc.
            if (u == 0 && tb && (tb & 7) == 0) {
                const int e = tb >> 3;
                #pragma unroll
                for (int mf = 0; mf < 8; ++mf) {
                    #pragma unroll
                    for (int r = 0; r < 4; ++r) {
                        int row = wm * 128 + mf * 16 + quad * 4 + r;
                        float wp = fmaxf(rws[row * 9 + e - 1], 1e-20f);
                        float wc = fmaxf(rws[row * 9 + e],     1e-20f);
                        float ratio = wp / wc;
                        #pragma unroll
                        for (int nf = 0; nf < 4; ++nf) facc[mf][nf][r] *= ratio;
                    }
                }
            }

            // ---- ph2: read av1(t); stage B(t+2)
            #pragma unroll
            for (int mf = 0; mf < 4; ++mf)
                fa1[cs][mf] = *(const bf16x8*)(Ab + aoff0 + (4 + mf) * 1024);
            gload_lds16(bsrc,           bd);
            gload_lds16(bsrc + 1048576, bd + 8192);

            asm volatile("s_barrier" ::: "memory");

            // ---- MFMA lo(t) from this tile's ph1 reads
            __builtin_amdgcn_s_setprio(1);
            #pragma unroll
            for (int mf = 0; mf < 4; ++mf)
                #pragma unroll
                for (int nf = 0; nf < 4; ++nf)
                    facc[mf][nf] = __builtin_amdgcn_mfma_f32_16x16x32_bf16(
                        av0[mf], fb[cs][nf], facc[mf][nf], 0, 0, 0);
            __builtin_amdgcn_s_setprio(0);
        }
    }

    // drain the pipeline: MFMA hi(255) (last tile wrote set 1: u=3 -> cs=1)
    {
        __builtin_amdgcn_s_setprio(1);
        #pragma unroll
        for (int mf = 0; mf < 4; ++mf)
            #pragma unroll
            for (int nf = 0; nf < 4; ++nf)
                facc[4 + mf][nf] = __builtin_amdgcn_mfma_f32_16x16x32_bf16(
                    fa1[1][mf], fb[1][nf], facc[4 + mf][nf], 0, 0, 0);
        __builtin_amdgcn_s_setprio(0);
    }

    // drain pending global_load_lds before epilogue / LDS reuse
    asm volatile("s_waitcnt vmcnt(0)" ::: "memory");

    // epilogue: out = GELU(facc * w_7 + bias)
    float bval[4];
    #pragma unroll
    for (int nf = 0; nf < 4; ++nf) bval[nf] = bias[f0 + wn * 64 + nf * 16 + l16];
    #pragma unroll
    for (int mf = 0; mf < 8; ++mf) {
        #pragma unroll
        for (int r = 0; r < 4; ++r) {
            int lrow = wm * 128 + mf * 16 + quad * 4 + r;
            int gm = m0 + lrow;
            float w7 = fmaxf(rws[lrow * 9 + 7], 1e-20f);
            #pragma unroll
            for (int nf = 0; nf < 4; ++nf) {
                float x = facc[mf][nf][r] * w7 + bval[nf];
                float gel = 0.5f * x * (1.0f + erff(x * 0.70710678118f));
                outp[(size_t)gm * DDIM + (f0 + wn * 64 + nf * 16 + l16)] = gel;
            }
        }
    }
}

// ---------------------------------------------------------------------------
extern "C" void kernel_launch(void* const* d_in, const int* in_sizes, int n_in,
                              void* d_out, int out_size, void* d_ws, size_t ws_size,
                              hipStream_t stream) {
    const float* h    = (const float*)d_in[0];   // [4,4096,1024]
    const float* Wr   = (const float*)d_in[1];   // [8,1024]
    const float* br   = (const float*)d_in[2];   // [8]
    const float* We   = (const float*)d_in[3];   // [8,1024,1024]
    const float* bias = (const float*)d_in[4];   // [1024]
    float* outp = (float*)d_out;
    char* ws = (char*)d_ws;

    __bf16* hbf = (__bf16*)ws;                                   // 32 MiB
    __bf16* Bp  = (__bf16*)(ws + (size_t)M_TOK * DDIM * 2);      // 16 MiB
    float*  rwp = (float*)(ws + (size_t)M_TOK * DDIM * 2
                              + (size_t)NEXP * DDIM * DDIM * 2); // 512 KiB

    hipLaunchKernelGGL(prep_kernel, dim3(CONV_BLOCKS + ROUTE_BLOCKS), dim3(256),
                       0, stream, h, Wr, br, We, hbf, rwp, Bp);
    hipLaunchKernelGGL(gemm_fused_kernel, dim3(256), dim3(512),
                       0, stream, hbf, Bp, rwp, bias, outp);
}